// Round 18
// baseline (211.874 us; speedup 1.0000x reference)
//
#include <hip/hip_runtime.h>
#include <math.h>

#define LTOT 2048
#define MROWS 4096   // BATCH * LTOT
#define CHK 64
#define NCH (LTOT / CHK)   // 32
#define SPAD 20

typedef short bf16x8 __attribute__((ext_vector_type(8)));
typedef float f32x4  __attribute__((ext_vector_type(4)));
typedef unsigned int u32x4 __attribute__((ext_vector_type(4)));
typedef unsigned short u16x8 __attribute__((ext_vector_type(8)));

__device__ __forceinline__ unsigned short bf16_rne(float f) {
  unsigned u = __float_as_uint(f);
  u += 0x7FFF + ((u >> 16) & 1);
  return (unsigned short)(u >> 16);
}
__device__ __forceinline__ float bf16_to_f(unsigned short h) {
  return __uint_as_float(((unsigned)h) << 16);
}
__device__ __forceinline__ float softplus_f(float x) {
  return (x > 15.f) ? x : log1pf(expf(x));
}
__device__ __forceinline__ float silu_f(float x) {
  return x / (1.f + expf(-x));
}

// ---------------------------------------------------------------------------
// k_prep: one launch for all preprocessing (segments as round 10).
// ---------------------------------------------------------------------------
__global__ __launch_bounds__(256) void k_prep(
    const float* __restrict__ x, const float* __restrict__ w1,
    const float* __restrict__ dw, const float* __restrict__ bw,
    const float* __restrict__ b1, const float* __restrict__ bb,
    unsigned short* __restrict__ xh, unsigned short* __restrict__ wfh,
    unsigned short* __restrict__ wdbAh, unsigned short* __restrict__ wdbAl,
    unsigned short* __restrict__ w1th, unsigned short* __restrict__ w1tl,
    float* __restrict__ bfull) {
  __shared__ float ts[64][65];
  const int blk = blockIdx.x;
  const int t = threadIdx.x;

  if (blk < 6144) {
    const float* src; unsigned short* h; int i;
    if (blk < 4096) { src = x;  h = xh;  i = blk * 256 + t; }
    else            { src = w1; h = wfh; i = (blk - 4096) * 256 + t; }
    const float4 v = ((const float4*)src)[i];
    ushort4 hh;
    hh.x = bf16_rne(v.x); hh.y = bf16_rne(v.y);
    hh.z = bf16_rne(v.z); hh.w = bf16_rne(v.w);
    ((ushort4*)h)[i] = hh;
  } else if (blk < 7296) {
    const float* src; unsigned short *h, *l; int i;
    if (blk < 7168) { src = dw; h = wdbAh; l = wdbAl; i = (blk - 6144) * 256 + t; }
    else            { src = bw; h = wdbAh + (size_t)1024*1024; l = wdbAl + (size_t)1024*1024;
                      i = (blk - 7168) * 256 + t; }
    const float4 v = ((const float4*)src)[i];
    ushort4 hh, ll;
    hh.x = bf16_rne(v.x); ll.x = bf16_rne(v.x - bf16_to_f(hh.x));
    hh.y = bf16_rne(v.y); ll.y = bf16_rne(v.y - bf16_to_f(hh.y));
    hh.z = bf16_rne(v.z); ll.z = bf16_rne(v.z - bf16_to_f(hh.z));
    hh.w = bf16_rne(v.w); ll.w = bf16_rne(v.w - bf16_to_f(hh.w));
    ((ushort4*)h)[i] = hh;
    ((ushort4*)l)[i] = ll;
  } else if (blk < 7552) {
    const int s = blk - 7296;
    const int k0 = (s & 15) * 64, j0 = (s >> 4) * 64;
    const int r = t >> 4, c4 = (t & 15) * 4;
    #pragma unroll
    for (int p = 0; p < 4; ++p) {
      const int row = p * 16 + r;
      const float4 v = *(const float4*)&w1[(size_t)(j0 + row) * 1024 + k0 + c4];
      ts[row][c4] = v.x; ts[row][c4+1] = v.y; ts[row][c4+2] = v.z; ts[row][c4+3] = v.w;
    }
    __syncthreads();
    #pragma unroll
    for (int p = 0; p < 4; ++p) {
      const int rk = p * 16 + r;
      ushort4 hh, ll;
      float f;
      f = ts[c4+0][rk]; hh.x = bf16_rne(f); ll.x = bf16_rne(f - bf16_to_f(hh.x));
      f = ts[c4+1][rk]; hh.y = bf16_rne(f); ll.y = bf16_rne(f - bf16_to_f(hh.y));
      f = ts[c4+2][rk]; hh.z = bf16_rne(f); ll.z = bf16_rne(f - bf16_to_f(hh.z));
      f = ts[c4+3][rk]; hh.w = bf16_rne(f); ll.w = bf16_rne(f - bf16_to_f(hh.w));
      *(ushort4*)&w1th[(size_t)(k0 + rk) * 1024 + j0 + c4] = hh;
      *(ushort4*)&w1tl[(size_t)(k0 + rk) * 1024 + j0 + c4] = ll;
    }
  } else {
    const int j = (blk - 7552) * 16 + (t >> 4);
    const int lane16 = t & 15;
    const float* W = (j < 1024) ? (dw + (size_t)j * 1024) : (bw + (size_t)(j - 1024) * 1024);
    float s = 0.f;
    for (int i = 0; i < 64; ++i) {
      const int k = lane16 + i * 16;
      s = fmaf(b1[k], W[k], s);
    }
    s += __shfl_xor(s, 8, 16);
    s += __shfl_xor(s, 4, 16);
    s += __shfl_xor(s, 2, 16);
    s += __shfl_xor(s, 1, 16);
    if (lane16 == 0) bfull[j] = s + ((j >= 1024) ? bb[j - 1024] : 0.f);
  }
}

// ---------------------------------------------------------------------------
// k_wcomp3: K-SPLIT weight composition GEMM (16x16x32 / 128^2, 3-product).
// Grid (8 n, 9 m, 4 ksplit). Emits fp32 partials; k_wred reduces + remaps.
// ---------------------------------------------------------------------------
__global__ __launch_bounds__(256) void k_wcomp3(
    const unsigned short* __restrict__ Ah_g, const unsigned short* __restrict__ Al_g,
    const unsigned short* __restrict__ Bh_g, const unsigned short* __restrict__ Bl_g,
    float* __restrict__ part) {
  __shared__ __align__(16) unsigned short LAh[128*32];
  __shared__ __align__(16) unsigned short LAl[128*32];
  __shared__ __align__(16) unsigned short LBh[128*32];
  __shared__ __align__(16) unsigned short LBl[128*32];
  const int t = threadIdx.x;
  const int wave = t >> 6, lane = t & 63;
  const int m0 = blockIdx.y * 128;
  const int n0 = blockIdx.x * 128;
  const int kb = blockIdx.z * 256;
  const int wr = wave >> 1, wc = wave & 1;
  const int ln = lane & 15, kq = lane >> 4;
  const int srow = lane >> 2, scol = (lane & 3) * 8;

  f32x4 acc[4][4];
  #pragma unroll
  for (int i = 0; i < 4; ++i)
    #pragma unroll
    for (int j = 0; j < 4; ++j) acc[i][j] = (f32x4){0.f, 0.f, 0.f, 0.f};

  const unsigned short* pAh = Ah_g + (size_t)m0 * 1024;
  const unsigned short* pAl = Al_g + (size_t)m0 * 1024;
  const unsigned short* pBh = Bh_g + (size_t)n0 * 1024;
  const unsigned short* pBl = Bl_g + (size_t)n0 * 1024;

  auto stage = [&](const unsigned short* g, unsigned short* lds, int k0) {
    #pragma unroll
    for (int r = 0; r < 2; ++r) {
      const unsigned short* gp = g + (size_t)(r * 64 + wave * 16 + srow) * 1024 + k0 + scol;
      unsigned short* lp = lds + (r * 64 + wave * 16) * 32;
      __builtin_amdgcn_global_load_lds((const __attribute__((address_space(1))) void*)gp,
                                       (__attribute__((address_space(3))) void*)lp, 16, 0, 0);
    }
  };

  for (int k0 = kb; k0 < kb + 256; k0 += 32) {
    __syncthreads();
    stage(pAh, LAh, k0);
    stage(pAl, LAl, k0);
    stage(pBh, LBh, k0);
    stage(pBl, LBl, k0);
    __syncthreads();
    bf16x8 ah[4], al[4], bh[4], bl[4];
    #pragma unroll
    for (int i = 0; i < 4; ++i) {
      const int ar = (wr * 64 + i * 16 + ln) * 32 + kq * 8;
      const int br = (wc * 64 + i * 16 + ln) * 32 + kq * 8;
      ah[i] = *(const bf16x8*)&LAh[ar];
      al[i] = *(const bf16x8*)&LAl[ar];
      bh[i] = *(const bf16x8*)&LBh[br];
      bl[i] = *(const bf16x8*)&LBl[br];
    }
    #pragma unroll
    for (int i = 0; i < 4; ++i)
      #pragma unroll
      for (int j = 0; j < 4; ++j) {
        acc[i][j] = __builtin_amdgcn_mfma_f32_16x16x32_bf16(ah[i], bh[j], acc[i][j], 0, 0, 0);
        acc[i][j] = __builtin_amdgcn_mfma_f32_16x16x32_bf16(ah[i], bl[j], acc[i][j], 0, 0, 0);
        acc[i][j] = __builtin_amdgcn_mfma_f32_16x16x32_bf16(al[i], bh[j], acc[i][j], 0, 0, 0);
      }
  }

  float* pout = part + (size_t)blockIdx.z * 1152 * 1024;
  #pragma unroll
  for (int nj = 0; nj < 4; ++nj) {
    const int kcol = n0 + wc * 64 + nj * 16 + ln;
    #pragma unroll
    for (int mi = 0; mi < 4; ++mi) {
      const int i = m0 + wr * 64 + mi * 16 + kq * 4;
      #pragma unroll
      for (int j = 0; j < 4; ++j)
        pout[(size_t)(i + j) * 1024 + kcol] = acc[mi][nj][j];
    }
  }
}

// ---------------------------------------------------------------------------
// k_wred: sum 4 fp32 partials -> bf16 -> wfull with row remap.
// ---------------------------------------------------------------------------
__global__ void k_wred(const float* __restrict__ part, unsigned short* __restrict__ outh) {
  const int e = blockIdx.x * 256 + threadIdx.x;       // [0, 294912)
  const int i = e >> 8;                               // row 0..1151
  const int k4 = (e & 255) * 4;
  const size_t stride = (size_t)1152 * 1024;
  const size_t off = (size_t)i * 1024 + k4;
  float4 s = *(const float4*)&part[off];
  #pragma unroll
  for (int p = 1; p < 4; ++p) {
    const float4 q = *(const float4*)&part[p * stride + off];
    s.x += q.x; s.y += q.y; s.z += q.z; s.w += q.w;
  }
  const int rbase = (i < 1024) ? (2176 + i) : (1024 + i);   // 2048+(i-1024)
  ushort4 hh;
  hh.x = bf16_rne(s.x); hh.y = bf16_rne(s.y); hh.z = bf16_rne(s.z); hh.w = bf16_rne(s.w);
  *(ushort4*)&outh[(size_t)rbase * 1024 + k4] = hh;
}

// ---------------------------------------------------------------------------
// k_mm_u: UNIFORM 1-product bf16 GEMM, C = x . wfull^T, N=3200.
// K-loop identical to round 16/17. NEW: epilogue goes through an LDS staging
// tile (fst[128][66] fp32, overlaid on the dead LA/LW arena) so stores are
// wide & coalesced: 2x ushort8 per row-chunk for bf16 u/v (was 32x 2B scalar
// stores/thread), 4x float4 for fp32 delta/Bm (was 32x dword). ~4-8x fewer
// store instructions, amortized over only 16 K-steps -> visible.
// ---------------------------------------------------------------------------
__global__ __launch_bounds__(256) void k_mm_u(
    const unsigned short* __restrict__ xh, const unsigned short* __restrict__ wfh,
    const float* __restrict__ b1, const float* __restrict__ bfull,
    unsigned short* __restrict__ u16, unsigned short* __restrict__ v16,
    float* __restrict__ delta, float* __restrict__ Bm) {
  __shared__ __align__(16) unsigned char SMEM[49152];   // 48 KB arena
  unsigned short* LA0 = (unsigned short*)SMEM;          // [128*64] bf16 16 KB
  unsigned short* LA1 = LA0 + 128 * 64;                 // 16 KB
  unsigned short* LW  = LA1 + 128 * 64;                 // 16 KB
  float* fst = (float*)SMEM;                            // [128][66] fp32 33.8 KB (epilogue)
  unsigned short* LAbuf[2] = {LA0, LA1};

  const int t = threadIdx.x;
  const int wave = t >> 6, lane = t & 63;
  const int flat = blockIdx.x;
  const int wg = (flat & 7) * 100 + (flat >> 3);
  const int tn = wg % 25;
  const int m0 = (wg / 25) * 128;
  const int wr = wave >> 1, wc = wave & 1;
  const int ln = lane & 15, kq = lane >> 4;
  const int srow = lane >> 3;
  const int scb  = ((lane & 7) ^ (lane >> 3)) * 8;

  int wdst[4]; size_t wsrc[4];
  #pragma unroll
  for (int q = 0; q < 4; ++q) {
    const int row = q * 32 + (t >> 3);
    const int blk = t & 7;
    wdst[q] = row * 64 + ((blk ^ (row & 7)) * 8);
    wsrc[q] = (size_t)row * 1024 + blk * 8;
  }

  f32x4 acc[4][4];
  #pragma unroll
  for (int i = 0; i < 4; ++i)
    #pragma unroll
    for (int j = 0; j < 4; ++j) acc[i][j] = (f32x4){0.f, 0.f, 0.f, 0.f};

  const unsigned short* pAh = xh + (size_t)m0 * 1024;
  const unsigned short* pW  = wfh + (size_t)(tn * 128) * 1024;

  auto stageA = [&](unsigned short* lds, int k0) {
    #pragma unroll
    for (int r = 0; r < 4; ++r) {
      const int rowb = wave * 32 + r * 8;
      const unsigned short* gp = pAh + (size_t)(rowb + srow) * 1024 + k0 + scb;
      unsigned short* lp = lds + rowb * 64;
      __builtin_amdgcn_global_load_lds((const __attribute__((address_space(1))) void*)gp,
                                       (__attribute__((address_space(3))) void*)lp, 16, 0, 0);
    }
  };

  u32x4 wreg[2][4];

  #pragma unroll
  for (int q = 0; q < 4; ++q) wreg[0][q] = *(const u32x4*)&pW[wsrc[q]];
  __builtin_amdgcn_sched_barrier(0);
  stageA(LA0, 0);
  __builtin_amdgcn_sched_barrier(0);
  #pragma unroll
  for (int q = 0; q < 4; ++q) wreg[1][q] = *(const u32x4*)&pW[wsrc[q] + 64];
  __builtin_amdgcn_sched_barrier(0);

  #pragma unroll
  for (int s = 0; s < 16; ++s) {
    const int cur = s & 1;
    if (s == 15) asm volatile("s_waitcnt vmcnt(0)" ::: "memory");
    else         asm volatile("s_waitcnt vmcnt(4)" ::: "memory");
    #pragma unroll
    for (int q = 0; q < 4; ++q) *(u32x4*)&LW[wdst[q]] = wreg[cur][q];
    asm volatile("s_waitcnt lgkmcnt(0)" ::: "memory");
    __builtin_amdgcn_sched_barrier(0);
    if (s < 15) stageA(LAbuf[cur ^ 1], (s + 1) * 64);
    __builtin_amdgcn_sched_barrier(0);
    if (s < 14) {
      #pragma unroll
      for (int q = 0; q < 4; ++q)
        wreg[cur][q] = *(const u32x4*)&pW[wsrc[q] + (size_t)(s + 2) * 64];
    }
    __builtin_amdgcn_sched_barrier(0);
    __builtin_amdgcn_s_barrier();
    __builtin_amdgcn_sched_barrier(0);

    const unsigned short* la = LAbuf[cur];
    #pragma unroll
    for (int kh = 0; kh < 2; ++kh) {
      bf16x8 ah[4], bh[4];
      #pragma unroll
      for (int i = 0; i < 4; ++i) {
        const int arow = wr * 64 + i * 16 + ln;
        const int brow = wc * 64 + i * 16 + ln;
        const int ablk = ((kh * 4 + kq) ^ (arow & 7)) * 8;
        const int bblk = ((kh * 4 + kq) ^ (brow & 7)) * 8;
        ah[i] = *(const bf16x8*)&la[arow * 64 + ablk];
        bh[i] = *(const bf16x8*)&LW[brow * 64 + bblk];
      }
      #pragma unroll
      for (int i = 0; i < 4; ++i)
        #pragma unroll
        for (int j = 0; j < 4; ++j)
          acc[i][j] = __builtin_amdgcn_mfma_f32_16x16x32_bf16(ah[i], bh[j], acc[i][j], 0, 0, 0);
    }

    if (s < 15) {
      __builtin_amdgcn_sched_barrier(0);
      __builtin_amdgcn_s_barrier();
    }
  }

  // -------- Epilogue via LDS staging (coalesced wide stores) --------
  // Per col-half h: waves with wc==h write acc(+bias, softplus for delta)
  // into fst[row][col] (row stride 66 kills bank conflicts), barrier, then
  // all 256 threads stream fst out with 16B stores.
  const bool isDelta = (tn >= 17);
  #pragma unroll
  for (int h = 0; h < 2; ++h) {
    __syncthreads();                    // fst region free (prev half / K-loop done)
    if (wc == h) {
      #pragma unroll
      for (int nj = 0; nj < 4; ++nj) {
        const int colg = tn * 128 + h * 64 + nj * 16 + ln;
        float bv;
        if (colg < 2048)      bv = b1[colg];
        else if (colg < 2176) bv = bfull[1024 + colg - 2048];
        else                  bv = bfull[colg - 2176];
        #pragma unroll
        for (int mi = 0; mi < 4; ++mi) {
          const int row = wr * 64 + mi * 16 + kq * 4;
          #pragma unroll
          for (int j = 0; j < 4; ++j) {
            float val = acc[mi][nj][j] + bv;
            if (isDelta) val = softplus_f(val);
            fst[(row + j) * 66 + h * 64 + nj * 16 + ln - h * 64] = val;  // col = nj*16+ln
          }
        }
      }
    }
    __syncthreads();
    // stream out: thread -> col-quarter q = t&3 (16 cols), rows r and r+64.
    const int q4 = (t & 3) * 16;
    const int r0 = t >> 2;              // 0..63
    const int colg0 = tn * 128 + h * 64 + q4;
    #pragma unroll
    for (int rr = 0; rr < 2; ++rr) {
      const int row = r0 + rr * 64;
      const float* src = &fst[row * 66 + q4];
      const int grow = m0 + row;
      if (tn < 8) {
        u16x8 o0, o1;
        #pragma unroll
        for (int c = 0; c < 8; ++c) { o0[c] = bf16_rne(src[c]); o1[c] = bf16_rne(src[8 + c]); }
        *(u16x8*)&u16[(size_t)grow * 1024 + colg0] = o0;
        *(u16x8*)&u16[(size_t)grow * 1024 + colg0 + 8] = o1;
      } else if (tn < 16) {
        u16x8 o0, o1;
        #pragma unroll
        for (int c = 0; c < 8; ++c) { o0[c] = bf16_rne(src[c]); o1[c] = bf16_rne(src[8 + c]); }
        *(u16x8*)&v16[(size_t)grow * 1024 + colg0 - 1024] = o0;
        *(u16x8*)&v16[(size_t)grow * 1024 + colg0 - 1024 + 8] = o1;
      } else if (tn == 16) {
        float* dst = &Bm[(size_t)grow * 128 + colg0 - 2048];
        #pragma unroll
        for (int c = 0; c < 4; ++c) *(float4*)&dst[c * 4] = *(const float4*)&src[c * 4];
      } else {
        float* dst = &delta[(size_t)grow * 1024 + colg0 - 2176];
        #pragma unroll
        for (int c = 0; c < 4; ++c) *(float4*)&dst[c * 4] = *(const float4*)&src[c * 4];
      }
    }
  }
}

// ---------------------------------------------------------------------------
// Chunk-parallel selective scan with fused depthwise conv+silu. u/v in bf16.
// ---------------------------------------------------------------------------
__global__ __launch_bounds__(256) void k_scanA(
    const float* __restrict__ delta, const unsigned short* __restrict__ u16,
    const float* __restrict__ Bm, const float* __restrict__ a_log,
    const float* __restrict__ cw, const float* __restrict__ cb,
    float* __restrict__ hend, float* __restrict__ Pp)
{
  __shared__ float sru[68][SPAD];
  __shared__ float sd[CHK][SPAD];
  __shared__ float sb[CHK][SPAD];
  __shared__ float suc[CHK][SPAD];
  const int t = threadIdx.x;
  const int bid = blockIdx.x;
  const int dblk = bid & 63;
  const int ch   = (bid >> 6) & (NCH - 1);
  const int b    = bid >> 11;
  const int d0 = dblk * 16;
  const int g  = dblk >> 3;
  const int l0 = ch * CHK;
  const size_t mb = (size_t)b * LTOT;

  {
    const int lrow = t >> 2;
    const int lc4  = (t & 3) * 4;
    const size_t r = mb + l0 + lrow;
    float4 rd = *(const float4*)&delta[r*1024 + d0 + lc4];
    float4 rb = *(const float4*)&Bm[r*128 + g*16 + lc4];
    *(float4*)&sd[lrow][lc4] = rd;
    *(float4*)&sb[lrow][lc4] = rb;
    const int sl = l0 + lrow - 4;
    float4 ru = {0.f, 0.f, 0.f, 0.f};
    if (sl >= 0) {
      const ushort4 rh = *(const ushort4*)&u16[(mb + sl)*1024 + d0 + lc4];
      ru.x = bf16_to_f(rh.x); ru.y = bf16_to_f(rh.y);
      ru.z = bf16_to_f(rh.z); ru.w = bf16_to_f(rh.w);
    }
    *(float4*)&sru[lrow][lc4] = ru;
    if (t < 16) {
      const int rr2 = 64 + (t >> 2);
      const int sl2 = l0 + rr2 - 4;
      const ushort4 rh = *(const ushort4*)&u16[(mb + sl2)*1024 + d0 + (t & 3) * 4];
      float4 r2 = {bf16_to_f(rh.x), bf16_to_f(rh.y), bf16_to_f(rh.z), bf16_to_f(rh.w)};
      *(float4*)&sru[rr2][(t & 3) * 4] = r2;
    }
  }
  __syncthreads();
  {
    const int c = t & 15;
    const int rb4 = (t >> 4) * 4;
    const float4 cwf = *(const float4*)&cw[(d0 + c) * 4];
    const float cbf = cb[d0 + c];
    #pragma unroll
    for (int q = 0; q < 4; ++q) {
      const int l = rb4 + q;
      float a = cbf;
      a = fmaf(sru[l+1][c], cwf.x, a);
      a = fmaf(sru[l+2][c], cwf.y, a);
      a = fmaf(sru[l+3][c], cwf.z, a);
      a = fmaf(sru[l+4][c], cwf.w, a);
      suc[l][c] = silu_f(a);
    }
  }
  __syncthreads();

  const int gi = t >> 4;
  const int n  = t & 15;
  const int d  = d0 + gi;
  const float A2 = -expf(a_log[d*16 + n]) * 1.4426950408889634f;

  float h = 0.f, P = 1.f;
  #pragma unroll 8
  for (int l = 0; l < CHK; ++l) {
    const float dv = sd[l][gi];
    const float uv = suc[l][gi];
    const float bv = sb[l][n];
    const float da = exp2f(dv * A2);
    P *= da;
    h = fmaf(da, h, dv * uv * bv);
  }
  const size_t idx = ((size_t)(b*NCH + ch) * 1024 + d) * 16 + n;
  hend[idx] = h;
  Pp[idx]   = P;
}

// ---------------------------------------------------------------------------
// k_scanB: chunk combine with register-batched ILP (round 17).
// ---------------------------------------------------------------------------
__global__ void k_scanB(float* hP, const float* __restrict__ Pp)
{
  const int t0 = blockIdx.x * 256 + threadIdx.x;   // 32768 strands
  const int b  = t0 >> 14;
  const int dn = t0 & 16383;
  const size_t base = ((size_t)b * NCH) << 14;
  float H = 0.f;
  #pragma unroll
  for (int half = 0; half < 2; ++half) {
    float hh[16], pp[16];
    #pragma unroll
    for (int c = 0; c < 16; ++c) {
      const size_t idx = base + (size_t)(half * 16 + c) * 16384 + dn;
      hh[c] = hP[idx];
      pp[c] = Pp[idx];
    }
    #pragma unroll
    for (int c = 0; c < 16; ++c) {
      const size_t idx = base + (size_t)(half * 16 + c) * 16384 + dn;
      hP[idx] = H;
      H = fmaf(pp[c], H, hh[c]);
    }
  }
}

__global__ __launch_bounds__(256) void k_scanC(
    const unsigned short* __restrict__ v16, const float* __restrict__ delta,
    const unsigned short* __restrict__ u16, const float* __restrict__ Bm,
    const float* __restrict__ a_log, const float* __restrict__ cp,
    const float* __restrict__ cw, const float* __restrict__ cb,
    const float* __restrict__ Hstart, float* __restrict__ out)
{
  __shared__ float sru[68][SPAD];
  __shared__ float sd[CHK][SPAD];
  __shared__ float sb[CHK][SPAD];
  __shared__ float suc[CHK][SPAD];
  __shared__ float sv[CHK][SPAD];
  __shared__ float sy[CHK][SPAD];
  const int t = threadIdx.x;
  const int bid = blockIdx.x;
  const int dblk = bid & 63;
  const int ch   = (bid >> 6) & (NCH - 1);
  const int b    = bid >> 11;
  const int d0 = dblk * 16;
  const int g  = dblk >> 3;
  const int l0 = ch * CHK;
  const size_t mb = (size_t)b * LTOT;

  {
    const int lrow = t >> 2;
    const int lc4  = (t & 3) * 4;
    const size_t r = mb + l0 + lrow;
    float4 rd = *(const float4*)&delta[r*1024 + d0 + lc4];
    float4 rb = *(const float4*)&Bm[r*128 + g*16 + lc4];
    const ushort4 rvh = *(const ushort4*)&v16[r*1024 + d0 + lc4];
    float4 rv = {bf16_to_f(rvh.x), bf16_to_f(rvh.y), bf16_to_f(rvh.z), bf16_to_f(rvh.w)};
    *(float4*)&sd[lrow][lc4] = rd;
    *(float4*)&sb[lrow][lc4] = rb;
    *(float4*)&sv[lrow][lc4] = rv;
    const int sl = l0 + lrow - 4;
    float4 ru = {0.f, 0.f, 0.f, 0.f};
    if (sl >= 0) {
      const ushort4 rh = *(const ushort4*)&u16[(mb + sl)*1024 + d0 + lc4];
      ru.x = bf16_to_f(rh.x); ru.y = bf16_to_f(rh.y);
      ru.z = bf16_to_f(rh.z); ru.w = bf16_to_f(rh.w);
    }
    *(float4*)&sru[lrow][lc4] = ru;
    if (t < 16) {
      const int rr2 = 64 + (t >> 2);
      const int sl2 = l0 + rr2 - 4;
      const ushort4 rh = *(const ushort4*)&u16[(mb + sl2)*1024 + d0 + (t & 3) * 4];
      float4 r2 = {bf16_to_f(rh.x), bf16_to_f(rh.y), bf16_to_f(rh.z), bf16_to_f(rh.w)};
      *(float4*)&sru[rr2][(t & 3) * 4] = r2;
    }
  }
  __syncthreads();
  {
    const int c = t & 15;
    const int rb4 = (t >> 4) * 4;
    const float4 cwf = *(const float4*)&cw[(d0 + c) * 4];
    const float cbf = cb[d0 + c];
    #pragma unroll
    for (int q = 0; q < 4; ++q) {
      const int l = rb4 + q;
      float a = cbf;
      a = fmaf(sru[l+1][c], cwf.x, a);
      a = fmaf(sru[l+2][c], cwf.y, a);
      a = fmaf(sru[l+3][c], cwf.z, a);
      a = fmaf(sru[l+4][c], cwf.w, a);
      suc[l][c] = silu_f(a);
    }
  }
  __syncthreads();

  const int gi = t >> 4;
  const int n  = t & 15;
  const int d  = d0 + gi;
  const float A2 = -expf(a_log[d*16 + n]) * 1.4426950408889634f;
  const float cc = cp[d*16 + n];
  float h = Hstart[((size_t)(b*NCH + ch) * 1024 + d) * 16 + n];

  #pragma unroll
  for (int l16 = 0; l16 < CHK; l16 += 16) {
    float p[16];
    #pragma unroll
    for (int j = 0; j < 16; ++j) {
      const int l = l16 + j;
      const float dv = sd[l][gi];
      const float uv = suc[l][gi];
      const float bv = sb[l][n];
      const float da = exp2f(dv * A2);
      h = fmaf(da, h, dv * uv * bv);
      p[j] = h * cc;
    }
    float q8[8];
    #pragma unroll
    for (int j = 0; j < 8; ++j) {
      const float send = (n & 8) ? p[j]     : p[j + 8];
      const float keep = (n & 8) ? p[j + 8] : p[j];
      q8[j] = keep + __shfl_xor(send, 8, 16);
    }
    float q4[4];
    #pragma unroll
    for (int j = 0; j < 4; ++j) {
      const float send = (n & 4) ? q8[j]     : q8[j + 4];
      const float keep = (n & 4) ? q8[j + 4] : q8[j];
      q4[j] = keep + __shfl_xor(send, 4, 16);
    }
    float q2[2];
    #pragma unroll
    for (int j = 0; j < 2; ++j) {
      const float send = (n & 2) ? q4[j]     : q4[j + 2];
      const float keep = (n & 2) ? q4[j + 2] : q4[j];
      q2[j] = keep + __shfl_xor(send, 2, 16);
    }
    {
      const float send = (n & 1) ? q2[0] : q2[1];
      const float keep = (n & 1) ? q2[1] : q2[0];
      sy[l16 + n][gi] = keep + __shfl_xor(send, 1, 16);
    }
  }

  __syncthreads();
  const int rr = t >> 4;
  const int c  = t & 15;
  #pragma unroll
  for (int k = 0; k < 4; ++k) {
    const int r = rr + k * 16;
    const float vv = sv[r][c];
    out[(mb + l0 + r) * 1024 + d0 + c] = sy[r][c] * silu_f(vv);
  }
}

// ---------------------------------------------------------------------------
extern "C" void kernel_launch(void* const* d_in, const int* in_sizes, int n_in,
                              void* d_out, int out_size, void* d_ws, size_t ws_size,
                              hipStream_t stream) {
  const float* x    = (const float*)d_in[0];
  const float* w1   = (const float*)d_in[1];
  const float* b1   = (const float*)d_in[2];
  const float* dw   = (const float*)d_in[3];
  const float* alog = (const float*)d_in[4];
  const float* bw   = (const float*)d_in[5];
  const float* bb   = (const float*)d_in[6];
  const float* cp   = (const float*)d_in[7];
  const float* cw   = (const float*)d_in[8];
  const float* cb   = (const float*)d_in[9];
  float* out = (float*)d_out;

  const size_t M4 = (size_t)MROWS * 1024;             // 4,194,304
  unsigned short* u16 = (unsigned short*)d_ws;        // [4096][1024] bf16 8 MB
  unsigned short* v16 = u16 + M4;                     // 8 MB
  float* delta = (float*)(v16 + M4);                  // 16 MB
  float* Bm    = delta + M4;                          // 2 MB
  unsigned short* xh  = (unsigned short*)(Bm + (size_t)MROWS * 128);  // 8 MB
  unsigned short* wfh = xh + M4;                      // [3200][1024] 6.25 MB
  float* bfull = (float*)(wfh + (size_t)3200 * 1024); // [1152] (pad to 2048)
  float* wpart = bfull + 2048;                        // [4][1152][1024] fp32 18.9 MB
  // pre-GEMM aliases in delta region (dead before delta is written):
  unsigned short* wdbAh = (unsigned short*)delta;
  unsigned short* wdbAl = wdbAh + (size_t)1152 * 1024;
  unsigned short* w1th  = wdbAl + (size_t)1152 * 1024;
  unsigned short* w1tl  = w1th + (size_t)1024 * 1024; // total 8.5 MB <= 16 MB
  // post-wred aliases (wpart dead after k_wred):
  float* hend = wpart;                                // 4 MB
  float* Pp   = hend + (size_t)2 * NCH * 1024 * 16;   // 4 MB (<= 18.9 MB)

  k_prep<<<7624, 256, 0, stream>>>(x, w1, dw, bw, b1, bb,
                                   xh, wfh, wdbAh, wdbAl, w1th, w1tl, bfull);
  k_wcomp3<<<dim3(8, 9, 4), 256, 0, stream>>>(wdbAh, wdbAl, w1th, w1tl, wpart);
  k_wred<<<1152, 256, 0, stream>>>(wpart, wfh);
  k_mm_u<<<800, 256, 0, stream>>>(xh, wfh, b1, bfull, u16, v16, delta, Bm);
  k_scanA<<<2 * NCH * 64, 256, 0, stream>>>(delta, u16, Bm, alog, cw, cb, hend, Pp);
  k_scanB<<<128, 256, 0, stream>>>(hend, Pp);
  k_scanC<<<2 * NCH * 64, 256, 0, stream>>>(v16, delta, u16, Bm, alog, cp, cw, cb, hend, out);
}

// Round 19
// 187.169 us; speedup vs baseline: 1.1320x; 1.1320x over previous
//
#include <hip/hip_runtime.h>
#include <math.h>

#define LTOT 2048
#define MROWS 4096   // BATCH * LTOT
#define CHK 64
#define NCH (LTOT / CHK)   // 32
#define SPAD 20

typedef short bf16x8 __attribute__((ext_vector_type(8)));
typedef float f32x4  __attribute__((ext_vector_type(4)));
typedef unsigned int u32x4 __attribute__((ext_vector_type(4)));

__device__ __forceinline__ unsigned short bf16_rne(float f) {
  unsigned u = __float_as_uint(f);
  u += 0x7FFF + ((u >> 16) & 1);
  return (unsigned short)(u >> 16);
}
__device__ __forceinline__ float bf16_to_f(unsigned short h) {
  return __uint_as_float(((unsigned)h) << 16);
}
__device__ __forceinline__ float softplus_f(float x) {
  return (x > 15.f) ? x : log1pf(expf(x));
}
__device__ __forceinline__ float silu_f(float x) {
  return x / (1.f + expf(-x));
}

// ---------------------------------------------------------------------------
// k_prep: one launch for all preprocessing.
// ---------------------------------------------------------------------------
__global__ __launch_bounds__(256) void k_prep(
    const float* __restrict__ x, const float* __restrict__ w1,
    const float* __restrict__ dw, const float* __restrict__ bw,
    const float* __restrict__ b1, const float* __restrict__ bb,
    unsigned short* __restrict__ xh, unsigned short* __restrict__ wfh,
    unsigned short* __restrict__ wdbAh, unsigned short* __restrict__ wdbAl,
    unsigned short* __restrict__ w1th, unsigned short* __restrict__ w1tl,
    float* __restrict__ bfull) {
  __shared__ float ts[64][65];
  const int blk = blockIdx.x;
  const int t = threadIdx.x;

  if (blk < 6144) {
    const float* src; unsigned short* h; int i;
    if (blk < 4096) { src = x;  h = xh;  i = blk * 256 + t; }
    else            { src = w1; h = wfh; i = (blk - 4096) * 256 + t; }
    const float4 v = ((const float4*)src)[i];
    ushort4 hh;
    hh.x = bf16_rne(v.x); hh.y = bf16_rne(v.y);
    hh.z = bf16_rne(v.z); hh.w = bf16_rne(v.w);
    ((ushort4*)h)[i] = hh;
  } else if (blk < 7296) {
    const float* src; unsigned short *h, *l; int i;
    if (blk < 7168) { src = dw; h = wdbAh; l = wdbAl; i = (blk - 6144) * 256 + t; }
    else            { src = bw; h = wdbAh + (size_t)1024*1024; l = wdbAl + (size_t)1024*1024;
                      i = (blk - 7168) * 256 + t; }
    const float4 v = ((const float4*)src)[i];
    ushort4 hh, ll;
    hh.x = bf16_rne(v.x); ll.x = bf16_rne(v.x - bf16_to_f(hh.x));
    hh.y = bf16_rne(v.y); ll.y = bf16_rne(v.y - bf16_to_f(hh.y));
    hh.z = bf16_rne(v.z); ll.z = bf16_rne(v.z - bf16_to_f(hh.z));
    hh.w = bf16_rne(v.w); ll.w = bf16_rne(v.w - bf16_to_f(hh.w));
    ((ushort4*)h)[i] = hh;
    ((ushort4*)l)[i] = ll;
  } else if (blk < 7552) {
    const int s = blk - 7296;
    const int k0 = (s & 15) * 64, j0 = (s >> 4) * 64;
    const int r = t >> 4, c4 = (t & 15) * 4;
    #pragma unroll
    for (int p = 0; p < 4; ++p) {
      const int row = p * 16 + r;
      const float4 v = *(const float4*)&w1[(size_t)(j0 + row) * 1024 + k0 + c4];
      ts[row][c4] = v.x; ts[row][c4+1] = v.y; ts[row][c4+2] = v.z; ts[row][c4+3] = v.w;
    }
    __syncthreads();
    #pragma unroll
    for (int p = 0; p < 4; ++p) {
      const int rk = p * 16 + r;
      ushort4 hh, ll;
      float f;
      f = ts[c4+0][rk]; hh.x = bf16_rne(f); ll.x = bf16_rne(f - bf16_to_f(hh.x));
      f = ts[c4+1][rk]; hh.y = bf16_rne(f); ll.y = bf16_rne(f - bf16_to_f(hh.y));
      f = ts[c4+2][rk]; hh.z = bf16_rne(f); ll.z = bf16_rne(f - bf16_to_f(hh.z));
      f = ts[c4+3][rk]; hh.w = bf16_rne(f); ll.w = bf16_rne(f - bf16_to_f(hh.w));
      *(ushort4*)&w1th[(size_t)(k0 + rk) * 1024 + j0 + c4] = hh;
      *(ushort4*)&w1tl[(size_t)(k0 + rk) * 1024 + j0 + c4] = ll;
    }
  } else {
    const int j = (blk - 7552) * 16 + (t >> 4);
    const int lane16 = t & 15;
    const float* W = (j < 1024) ? (dw + (size_t)j * 1024) : (bw + (size_t)(j - 1024) * 1024);
    float s = 0.f;
    for (int i = 0; i < 64; ++i) {
      const int k = lane16 + i * 16;
      s = fmaf(b1[k], W[k], s);
    }
    s += __shfl_xor(s, 8, 16);
    s += __shfl_xor(s, 4, 16);
    s += __shfl_xor(s, 2, 16);
    s += __shfl_xor(s, 1, 16);
    if (lane16 == 0) bfull[j] = s + ((j >= 1024) ? bb[j - 1024] : 0.f);
  }
}

// ---------------------------------------------------------------------------
// k_wcomp3: K-SPLIT weight composition GEMM (16x16x32 / 128^2, 3-product).
// Grid (8 n, 9 m, 4 ksplit). Emits fp32 partials; k_wred reduces + remaps.
// ---------------------------------------------------------------------------
__global__ __launch_bounds__(256) void k_wcomp3(
    const unsigned short* __restrict__ Ah_g, const unsigned short* __restrict__ Al_g,
    const unsigned short* __restrict__ Bh_g, const unsigned short* __restrict__ Bl_g,
    float* __restrict__ part) {
  __shared__ __align__(16) unsigned short LAh[128*32];
  __shared__ __align__(16) unsigned short LAl[128*32];
  __shared__ __align__(16) unsigned short LBh[128*32];
  __shared__ __align__(16) unsigned short LBl[128*32];
  const int t = threadIdx.x;
  const int wave = t >> 6, lane = t & 63;
  const int m0 = blockIdx.y * 128;
  const int n0 = blockIdx.x * 128;
  const int kb = blockIdx.z * 256;
  const int wr = wave >> 1, wc = wave & 1;
  const int ln = lane & 15, kq = lane >> 4;
  const int srow = lane >> 2, scol = (lane & 3) * 8;

  f32x4 acc[4][4];
  #pragma unroll
  for (int i = 0; i < 4; ++i)
    #pragma unroll
    for (int j = 0; j < 4; ++j) acc[i][j] = (f32x4){0.f, 0.f, 0.f, 0.f};

  const unsigned short* pAh = Ah_g + (size_t)m0 * 1024;
  const unsigned short* pAl = Al_g + (size_t)m0 * 1024;
  const unsigned short* pBh = Bh_g + (size_t)n0 * 1024;
  const unsigned short* pBl = Bl_g + (size_t)n0 * 1024;

  auto stage = [&](const unsigned short* g, unsigned short* lds, int k0) {
    #pragma unroll
    for (int r = 0; r < 2; ++r) {
      const unsigned short* gp = g + (size_t)(r * 64 + wave * 16 + srow) * 1024 + k0 + scol;
      unsigned short* lp = lds + (r * 64 + wave * 16) * 32;
      __builtin_amdgcn_global_load_lds((const __attribute__((address_space(1))) void*)gp,
                                       (__attribute__((address_space(3))) void*)lp, 16, 0, 0);
    }
  };

  for (int k0 = kb; k0 < kb + 256; k0 += 32) {
    __syncthreads();
    stage(pAh, LAh, k0);
    stage(pAl, LAl, k0);
    stage(pBh, LBh, k0);
    stage(pBl, LBl, k0);
    __syncthreads();
    bf16x8 ah[4], al[4], bh[4], bl[4];
    #pragma unroll
    for (int i = 0; i < 4; ++i) {
      const int ar = (wr * 64 + i * 16 + ln) * 32 + kq * 8;
      const int br = (wc * 64 + i * 16 + ln) * 32 + kq * 8;
      ah[i] = *(const bf16x8*)&LAh[ar];
      al[i] = *(const bf16x8*)&LAl[ar];
      bh[i] = *(const bf16x8*)&LBh[br];
      bl[i] = *(const bf16x8*)&LBl[br];
    }
    #pragma unroll
    for (int i = 0; i < 4; ++i)
      #pragma unroll
      for (int j = 0; j < 4; ++j) {
        acc[i][j] = __builtin_amdgcn_mfma_f32_16x16x32_bf16(ah[i], bh[j], acc[i][j], 0, 0, 0);
        acc[i][j] = __builtin_amdgcn_mfma_f32_16x16x32_bf16(ah[i], bl[j], acc[i][j], 0, 0, 0);
        acc[i][j] = __builtin_amdgcn_mfma_f32_16x16x32_bf16(al[i], bh[j], acc[i][j], 0, 0, 0);
      }
  }

  float* pout = part + (size_t)blockIdx.z * 1152 * 1024;
  #pragma unroll
  for (int nj = 0; nj < 4; ++nj) {
    const int kcol = n0 + wc * 64 + nj * 16 + ln;
    #pragma unroll
    for (int mi = 0; mi < 4; ++mi) {
      const int i = m0 + wr * 64 + mi * 16 + kq * 4;
      #pragma unroll
      for (int j = 0; j < 4; ++j)
        pout[(size_t)(i + j) * 1024 + kcol] = acc[mi][nj][j];
    }
  }
}

// ---------------------------------------------------------------------------
// k_wred: sum 4 fp32 partials -> bf16 -> wfull with row remap.
// ---------------------------------------------------------------------------
__global__ void k_wred(const float* __restrict__ part, unsigned short* __restrict__ outh) {
  const int e = blockIdx.x * 256 + threadIdx.x;       // [0, 294912)
  const int i = e >> 8;                               // row 0..1151
  const int k4 = (e & 255) * 4;
  const size_t stride = (size_t)1152 * 1024;
  const size_t off = (size_t)i * 1024 + k4;
  float4 s = *(const float4*)&part[off];
  #pragma unroll
  for (int p = 1; p < 4; ++p) {
    const float4 q = *(const float4*)&part[p * stride + off];
    s.x += q.x; s.y += q.y; s.z += q.z; s.w += q.w;
  }
  const int rbase = (i < 1024) ? (2176 + i) : (1024 + i);   // 2048+(i-1024)
  ushort4 hh;
  hh.x = bf16_rne(s.x); hh.y = bf16_rne(s.y); hh.z = bf16_rne(s.z); hh.w = bf16_rne(s.w);
  *(ushort4*)&outh[(size_t)rbase * 1024 + k4] = hh;
}

// ---------------------------------------------------------------------------
// k_mm_u: UNIFORM 1-product bf16 GEMM, C = x . wfull^T, N=3200.
// BK=64, XOR-swizzled LDS. A: gload_lds double-buffered. W: reg-staged 2
// K-steps ahead, published into a single LW buffer. LDS 48 KB -> 3 blocks/CU.
// (Round-17 state — measured floor of the 128^2 2-phase structure.)
// ---------------------------------------------------------------------------
__global__ __launch_bounds__(256) void k_mm_u(
    const unsigned short* __restrict__ xh, const unsigned short* __restrict__ wfh,
    const float* __restrict__ b1, const float* __restrict__ bfull,
    unsigned short* __restrict__ u16, unsigned short* __restrict__ v16,
    float* __restrict__ delta, float* __restrict__ Bm) {
  __shared__ __align__(16) unsigned short LA[2][128*64];
  __shared__ __align__(16) unsigned short LW[128*64];
  const int t = threadIdx.x;
  const int wave = t >> 6, lane = t & 63;
  const int flat = blockIdx.x;
  const int wg = (flat & 7) * 100 + (flat >> 3);
  const int tn = wg % 25;
  const int m0 = (wg / 25) * 128;
  const int wr = wave >> 1, wc = wave & 1;
  const int ln = lane & 15, kq = lane >> 4;
  const int srow = lane >> 3;
  const int scb  = ((lane & 7) ^ (lane >> 3)) * 8;

  int wdst[4]; size_t wsrc[4];
  #pragma unroll
  for (int q = 0; q < 4; ++q) {
    const int row = q * 32 + (t >> 3);
    const int blk = t & 7;
    wdst[q] = row * 64 + ((blk ^ (row & 7)) * 8);
    wsrc[q] = (size_t)row * 1024 + blk * 8;
  }

  f32x4 acc[4][4];
  #pragma unroll
  for (int i = 0; i < 4; ++i)
    #pragma unroll
    for (int j = 0; j < 4; ++j) acc[i][j] = (f32x4){0.f, 0.f, 0.f, 0.f};

  const unsigned short* pAh = xh + (size_t)m0 * 1024;
  const unsigned short* pW  = wfh + (size_t)(tn * 128) * 1024;

  auto stageA = [&](unsigned short* lds, int k0) {
    #pragma unroll
    for (int r = 0; r < 4; ++r) {
      const int rowb = wave * 32 + r * 8;
      const unsigned short* gp = pAh + (size_t)(rowb + srow) * 1024 + k0 + scb;
      unsigned short* lp = lds + rowb * 64;
      __builtin_amdgcn_global_load_lds((const __attribute__((address_space(1))) void*)gp,
                                       (__attribute__((address_space(3))) void*)lp, 16, 0, 0);
    }
  };

  u32x4 wreg[2][4];

  #pragma unroll
  for (int q = 0; q < 4; ++q) wreg[0][q] = *(const u32x4*)&pW[wsrc[q]];
  __builtin_amdgcn_sched_barrier(0);
  stageA(LA[0], 0);
  __builtin_amdgcn_sched_barrier(0);
  #pragma unroll
  for (int q = 0; q < 4; ++q) wreg[1][q] = *(const u32x4*)&pW[wsrc[q] + 64];
  __builtin_amdgcn_sched_barrier(0);

  #pragma unroll
  for (int s = 0; s < 16; ++s) {
    const int cur = s & 1;
    if (s == 15) asm volatile("s_waitcnt vmcnt(0)" ::: "memory");
    else         asm volatile("s_waitcnt vmcnt(4)" ::: "memory");
    #pragma unroll
    for (int q = 0; q < 4; ++q) *(u32x4*)&LW[wdst[q]] = wreg[cur][q];
    asm volatile("s_waitcnt lgkmcnt(0)" ::: "memory");
    __builtin_amdgcn_sched_barrier(0);
    if (s < 15) stageA(LA[cur ^ 1], (s + 1) * 64);
    __builtin_amdgcn_sched_barrier(0);
    if (s < 14) {
      #pragma unroll
      for (int q = 0; q < 4; ++q)
        wreg[cur][q] = *(const u32x4*)&pW[wsrc[q] + (size_t)(s + 2) * 64];
    }
    __builtin_amdgcn_sched_barrier(0);
    __builtin_amdgcn_s_barrier();
    __builtin_amdgcn_sched_barrier(0);

    const unsigned short* la = LA[cur];
    #pragma unroll
    for (int kh = 0; kh < 2; ++kh) {
      bf16x8 ah[4], bh[4];
      #pragma unroll
      for (int i = 0; i < 4; ++i) {
        const int arow = wr * 64 + i * 16 + ln;
        const int brow = wc * 64 + i * 16 + ln;
        const int ablk = ((kh * 4 + kq) ^ (arow & 7)) * 8;
        const int bblk = ((kh * 4 + kq) ^ (brow & 7)) * 8;
        ah[i] = *(const bf16x8*)&la[arow * 64 + ablk];
        bh[i] = *(const bf16x8*)&LW[brow * 64 + bblk];
      }
      #pragma unroll
      for (int i = 0; i < 4; ++i)
        #pragma unroll
        for (int j = 0; j < 4; ++j)
          acc[i][j] = __builtin_amdgcn_mfma_f32_16x16x32_bf16(ah[i], bh[j], acc[i][j], 0, 0, 0);
    }

    if (s < 15) {
      __builtin_amdgcn_sched_barrier(0);
      __builtin_amdgcn_s_barrier();
    }
  }

  #pragma unroll
  for (int nj = 0; nj < 4; ++nj) {
    const int colg = tn * 128 + wc * 64 + nj * 16 + ln;
    float bv;
    if (colg < 2048)      bv = b1[colg];
    else if (colg < 2176) bv = bfull[1024 + colg - 2048];
    else                  bv = bfull[colg - 2176];
    #pragma unroll
    for (int mi = 0; mi < 4; ++mi) {
      const int row = m0 + wr * 64 + mi * 16 + kq * 4;
      #pragma unroll
      for (int j = 0; j < 4; ++j) {
        const float val = acc[mi][nj][j] + bv;
        if (tn < 8)        u16[(size_t)(row + j) * 1024 + colg] = bf16_rne(val);
        else if (tn < 16)  v16[(size_t)(row + j) * 1024 + colg - 1024] = bf16_rne(val);
        else if (tn == 16) Bm[(size_t)(row + j) * 128 + colg - 2048] = val;
        else               delta[(size_t)(row + j) * 1024 + colg - 2176] = softplus_f(val);
      }
    }
  }
}

// ---------------------------------------------------------------------------
// Chunk-parallel selective scan with fused depthwise conv+silu. u/v in bf16.
// ---------------------------------------------------------------------------
__global__ __launch_bounds__(256) void k_scanA(
    const float* __restrict__ delta, const unsigned short* __restrict__ u16,
    const float* __restrict__ Bm, const float* __restrict__ a_log,
    const float* __restrict__ cw, const float* __restrict__ cb,
    float* __restrict__ hend, float* __restrict__ Pp)
{
  __shared__ float sru[68][SPAD];
  __shared__ float sd[CHK][SPAD];
  __shared__ float sb[CHK][SPAD];
  __shared__ float suc[CHK][SPAD];
  const int t = threadIdx.x;
  const int bid = blockIdx.x;
  const int dblk = bid & 63;
  const int ch   = (bid >> 6) & (NCH - 1);
  const int b    = bid >> 11;
  const int d0 = dblk * 16;
  const int g  = dblk >> 3;
  const int l0 = ch * CHK;
  const size_t mb = (size_t)b * LTOT;

  {
    const int lrow = t >> 2;
    const int lc4  = (t & 3) * 4;
    const size_t r = mb + l0 + lrow;
    float4 rd = *(const float4*)&delta[r*1024 + d0 + lc4];
    float4 rb = *(const float4*)&Bm[r*128 + g*16 + lc4];
    *(float4*)&sd[lrow][lc4] = rd;
    *(float4*)&sb[lrow][lc4] = rb;
    const int sl = l0 + lrow - 4;
    float4 ru = {0.f, 0.f, 0.f, 0.f};
    if (sl >= 0) {
      const ushort4 rh = *(const ushort4*)&u16[(mb + sl)*1024 + d0 + lc4];
      ru.x = bf16_to_f(rh.x); ru.y = bf16_to_f(rh.y);
      ru.z = bf16_to_f(rh.z); ru.w = bf16_to_f(rh.w);
    }
    *(float4*)&sru[lrow][lc4] = ru;
    if (t < 16) {
      const int rr2 = 64 + (t >> 2);
      const int sl2 = l0 + rr2 - 4;
      const ushort4 rh = *(const ushort4*)&u16[(mb + sl2)*1024 + d0 + (t & 3) * 4];
      float4 r2 = {bf16_to_f(rh.x), bf16_to_f(rh.y), bf16_to_f(rh.z), bf16_to_f(rh.w)};
      *(float4*)&sru[rr2][(t & 3) * 4] = r2;
    }
  }
  __syncthreads();
  {
    const int c = t & 15;
    const int rb4 = (t >> 4) * 4;
    const float4 cwf = *(const float4*)&cw[(d0 + c) * 4];
    const float cbf = cb[d0 + c];
    #pragma unroll
    for (int q = 0; q < 4; ++q) {
      const int l = rb4 + q;
      float a = cbf;
      a = fmaf(sru[l+1][c], cwf.x, a);
      a = fmaf(sru[l+2][c], cwf.y, a);
      a = fmaf(sru[l+3][c], cwf.z, a);
      a = fmaf(sru[l+4][c], cwf.w, a);
      suc[l][c] = silu_f(a);
    }
  }
  __syncthreads();

  const int gi = t >> 4;
  const int n  = t & 15;
  const int d  = d0 + gi;
  const float A2 = -expf(a_log[d*16 + n]) * 1.4426950408889634f;

  float h = 0.f, P = 1.f;
  #pragma unroll 8
  for (int l = 0; l < CHK; ++l) {
    const float dv = sd[l][gi];
    const float uv = suc[l][gi];
    const float bv = sb[l][n];
    const float da = exp2f(dv * A2);
    P *= da;
    h = fmaf(da, h, dv * uv * bv);
  }
  const size_t idx = ((size_t)(b*NCH + ch) * 1024 + d) * 16 + n;
  hend[idx] = h;
  Pp[idx]   = P;
}

// ---------------------------------------------------------------------------
// k_scanB: chunk combine with register-batched ILP.
// ---------------------------------------------------------------------------
__global__ void k_scanB(float* hP, const float* __restrict__ Pp)
{
  const int t0 = blockIdx.x * 256 + threadIdx.x;   // 32768 strands
  const int b  = t0 >> 14;
  const int dn = t0 & 16383;
  const size_t base = ((size_t)b * NCH) << 14;
  float H = 0.f;
  #pragma unroll
  for (int half = 0; half < 2; ++half) {
    float hh[16], pp[16];
    #pragma unroll
    for (int c = 0; c < 16; ++c) {
      const size_t idx = base + (size_t)(half * 16 + c) * 16384 + dn;
      hh[c] = hP[idx];
      pp[c] = Pp[idx];
    }
    #pragma unroll
    for (int c = 0; c < 16; ++c) {
      const size_t idx = base + (size_t)(half * 16 + c) * 16384 + dn;
      hP[idx] = H;
      H = fmaf(pp[c], H, hh[c]);
    }
  }
}

__global__ __launch_bounds__(256) void k_scanC(
    const unsigned short* __restrict__ v16, const float* __restrict__ delta,
    const unsigned short* __restrict__ u16, const float* __restrict__ Bm,
    const float* __restrict__ a_log, const float* __restrict__ cp,
    const float* __restrict__ cw, const float* __restrict__ cb,
    const float* __restrict__ Hstart, float* __restrict__ out)
{
  __shared__ float sru[68][SPAD];
  __shared__ float sd[CHK][SPAD];
  __shared__ float sb[CHK][SPAD];
  __shared__ float suc[CHK][SPAD];
  __shared__ float sv[CHK][SPAD];
  __shared__ float sy[CHK][SPAD];
  const int t = threadIdx.x;
  const int bid = blockIdx.x;
  const int dblk = bid & 63;
  const int ch   = (bid >> 6) & (NCH - 1);
  const int b    = bid >> 11;
  const int d0 = dblk * 16;
  const int g  = dblk >> 3;
  const int l0 = ch * CHK;
  const size_t mb = (size_t)b * LTOT;

  {
    const int lrow = t >> 2;
    const int lc4  = (t & 3) * 4;
    const size_t r = mb + l0 + lrow;
    float4 rd = *(const float4*)&delta[r*1024 + d0 + lc4];
    float4 rb = *(const float4*)&Bm[r*128 + g*16 + lc4];
    const ushort4 rvh = *(const ushort4*)&v16[r*1024 + d0 + lc4];
    float4 rv = {bf16_to_f(rvh.x), bf16_to_f(rvh.y), bf16_to_f(rvh.z), bf16_to_f(rvh.w)};
    *(float4*)&sd[lrow][lc4] = rd;
    *(float4*)&sb[lrow][lc4] = rb;
    *(float4*)&sv[lrow][lc4] = rv;
    const int sl = l0 + lrow - 4;
    float4 ru = {0.f, 0.f, 0.f, 0.f};
    if (sl >= 0) {
      const ushort4 rh = *(const ushort4*)&u16[(mb + sl)*1024 + d0 + lc4];
      ru.x = bf16_to_f(rh.x); ru.y = bf16_to_f(rh.y);
      ru.z = bf16_to_f(rh.z); ru.w = bf16_to_f(rh.w);
    }
    *(float4*)&sru[lrow][lc4] = ru;
    if (t < 16) {
      const int rr2 = 64 + (t >> 2);
      const int sl2 = l0 + rr2 - 4;
      const ushort4 rh = *(const ushort4*)&u16[(mb + sl2)*1024 + d0 + (t & 3) * 4];
      float4 r2 = {bf16_to_f(rh.x), bf16_to_f(rh.y), bf16_to_f(rh.z), bf16_to_f(rh.w)};
      *(float4*)&sru[rr2][(t & 3) * 4] = r2;
    }
  }
  __syncthreads();
  {
    const int c = t & 15;
    const int rb4 = (t >> 4) * 4;
    const float4 cwf = *(const float4*)&cw[(d0 + c) * 4];
    const float cbf = cb[d0 + c];
    #pragma unroll
    for (int q = 0; q < 4; ++q) {
      const int l = rb4 + q;
      float a = cbf;
      a = fmaf(sru[l+1][c], cwf.x, a);
      a = fmaf(sru[l+2][c], cwf.y, a);
      a = fmaf(sru[l+3][c], cwf.z, a);
      a = fmaf(sru[l+4][c], cwf.w, a);
      suc[l][c] = silu_f(a);
    }
  }
  __syncthreads();

  const int gi = t >> 4;
  const int n  = t & 15;
  const int d  = d0 + gi;
  const float A2 = -expf(a_log[d*16 + n]) * 1.4426950408889634f;
  const float cc = cp[d*16 + n];
  float h = Hstart[((size_t)(b*NCH + ch) * 1024 + d) * 16 + n];

  #pragma unroll
  for (int l16 = 0; l16 < CHK; l16 += 16) {
    float p[16];
    #pragma unroll
    for (int j = 0; j < 16; ++j) {
      const int l = l16 + j;
      const float dv = sd[l][gi];
      const float uv = suc[l][gi];
      const float bv = sb[l][n];
      const float da = exp2f(dv * A2);
      h = fmaf(da, h, dv * uv * bv);
      p[j] = h * cc;
    }
    float q8[8];
    #pragma unroll
    for (int j = 0; j < 8; ++j) {
      const float send = (n & 8) ? p[j]     : p[j + 8];
      const float keep = (n & 8) ? p[j + 8] : p[j];
      q8[j] = keep + __shfl_xor(send, 8, 16);
    }
    float q4[4];
    #pragma unroll
    for (int j = 0; j < 4; ++j) {
      const float send = (n & 4) ? q8[j]     : q8[j + 4];
      const float keep = (n & 4) ? q8[j + 4] : q8[j];
      q4[j] = keep + __shfl_xor(send, 4, 16);
    }
    float q2[2];
    #pragma unroll
    for (int j = 0; j < 2; ++j) {
      const float send = (n & 2) ? q4[j]     : q4[j + 2];
      const float keep = (n & 2) ? q4[j + 2] : q4[j];
      q2[j] = keep + __shfl_xor(send, 2, 16);
    }
    {
      const float send = (n & 1) ? q2[0] : q2[1];
      const float keep = (n & 1) ? q2[1] : q2[0];
      sy[l16 + n][gi] = keep + __shfl_xor(send, 1, 16);
    }
  }

  __syncthreads();
  const int rr = t >> 4;
  const int c  = t & 15;
  #pragma unroll
  for (int k = 0; k < 4; ++k) {
    const int r = rr + k * 16;
    const float vv = sv[r][c];
    out[(mb + l0 + r) * 1024 + d0 + c] = sy[r][c] * silu_f(vv);
  }
}

// ---------------------------------------------------------------------------
extern "C" void kernel_launch(void* const* d_in, const int* in_sizes, int n_in,
                              void* d_out, int out_size, void* d_ws, size_t ws_size,
                              hipStream_t stream) {
  const float* x    = (const float*)d_in[0];
  const float* w1   = (const float*)d_in[1];
  const float* b1   = (const float*)d_in[2];
  const float* dw   = (const float*)d_in[3];
  const float* alog = (const float*)d_in[4];
  const float* bw   = (const float*)d_in[5];
  const float* bb   = (const float*)d_in[6];
  const float* cp   = (const float*)d_in[7];
  const float* cw   = (const float*)d_in[8];
  const float* cb   = (const float*)d_in[9];
  float* out = (float*)d_out;

  const size_t M4 = (size_t)MROWS * 1024;             // 4,194,304
  unsigned short* u16 = (unsigned short*)d_ws;        // [4096][1024] bf16 8 MB
  unsigned short* v16 = u16 + M4;                     // 8 MB
  float* delta = (float*)(v16 + M4);                  // 16 MB
  float* Bm    = delta + M4;                          // 2 MB
  unsigned short* xh  = (unsigned short*)(Bm + (size_t)MROWS * 128);  // 8 MB
  unsigned short* wfh = xh + M4;                      // [3200][1024] 6.25 MB
  float* bfull = (float*)(wfh + (size_t)3200 * 1024); // [1152] (pad to 2048)
  float* wpart = bfull + 2048;                        // [4][1152][1024] fp32 18.9 MB
  // pre-GEMM aliases in delta region (dead before delta is written):
  unsigned short* wdbAh = (unsigned short*)delta;
  unsigned short* wdbAl = wdbAh + (size_t)1152 * 1024;
  unsigned short* w1th  = wdbAl + (size_t)1152 * 1024;
  unsigned short* w1tl  = w1th + (size_t)1024 * 1024; // total 8.5 MB <= 16 MB
  // post-wred aliases (wpart dead after k_wred):
  float* hend = wpart;                                // 4 MB
  float* Pp   = hend + (size_t)2 * NCH * 1024 * 16;   // 4 MB (<= 18.9 MB)

  k_prep<<<7624, 256, 0, stream>>>(x, w1, dw, bw, b1, bb,
                                   xh, wfh, wdbAh, wdbAl, w1th, w1tl, bfull);
  k_wcomp3<<<dim3(8, 9, 4), 256, 0, stream>>>(wdbAh, wdbAl, w1th, w1tl, wpart);
  k_wred<<<1152, 256, 0, stream>>>(wpart, wfh);
  k_mm_u<<<800, 256, 0, stream>>>(xh, wfh, b1, bfull, u16, v16, delta, Bm);
  k_scanA<<<2 * NCH * 64, 256, 0, stream>>>(delta, u16, Bm, alog, cw, cb, hend, Pp);
  k_scanB<<<128, 256, 0, stream>>>(hend, Pp);
  k_scanC<<<2 * NCH * 64, 256, 0, stream>>>(v16, delta, u16, Bm, alog, cp, cw, cb, hend, out);
}